// Round 5
// baseline (248.705 us; speedup 1.0000x reference)
//
#include <hip/hip_runtime.h>
#include <stdint.h>

// Problem dims
#define TOKENS 8192      // 4*2048
#define IN_F   3072
#define PAD_F  4096
#define N_OUT  4096
#define K_DIM  4096

using i32x4  = __attribute__((ext_vector_type(4))) int;
using i32x16 = __attribute__((ext_vector_type(16))) int;

// -------- workspace layout (bytes) --------
#define Q_OFF    0
#define WQ_OFF   33554432
#define AINV_OFF 50331648
#define PART_OFF 50364416
#define WSC_OFF  50380800

__device__ __forceinline__ void gload_lds16(const void* g, void* l) {
    __builtin_amdgcn_global_load_lds(
        (__attribute__((address_space(1))) void*)(void*)g,
        (__attribute__((address_space(3))) void*)l,
        16, 0, 0);
}

// ---------------- weight absmean: partial sums ----------------
__global__ __launch_bounds__(256) void k_wabs(const float* __restrict__ w,
                                              float* __restrict__ partial) {
    int tid = threadIdx.x;
    const float4* w4 = (const float4*)(w + (size_t)blockIdx.x * 4096);
    float s = 0.f;
#pragma unroll
    for (int i = 0; i < 4; ++i) {
        float4 v = w4[tid + i * 256];
        s += fabsf(v.x) + fabsf(v.y) + fabsf(v.z) + fabsf(v.w);
    }
#pragma unroll
    for (int o = 32; o > 0; o >>= 1) s += __shfl_xor(s, o);
    __shared__ float rb[4];
    if ((tid & 63) == 0) rb[tid >> 6] = s;
    __syncthreads();
    if (tid == 0) partial[blockIdx.x] = rb[0] + rb[1] + rb[2] + rb[3];
}

// ---------------- finalize weight scale ----------------
__global__ __launch_bounds__(256) void k_wscale(const float* __restrict__ partial,
                                                float* __restrict__ wsp) {
    int tid = threadIdx.x;
    float s = 0.f;
#pragma unroll
    for (int i = 0; i < 16; ++i) s += partial[tid + i * 256];
#pragma unroll
    for (int o = 32; o > 0; o >>= 1) s += __shfl_xor(s, o);
    __shared__ float rb[4];
    if ((tid & 63) == 0) rb[tid >> 6] = s;
    __syncthreads();
    if (tid == 0)
        wsp[0] = fmaxf((rb[0] + rb[1] + rb[2] + rb[3]) * (1.0f / 16777216.0f), 1e-5f);
}

// ---------------- ternary weight quant ----------------
__global__ __launch_bounds__(256) void k_wquant(const float* __restrict__ w,
                                                const float* __restrict__ wsp,
                                                unsigned int* __restrict__ wq) {
    int idx = blockIdx.x * 256 + threadIdx.x;   // float4 group index
    float ws = wsp[0];
    float4 v = ((const float4*)w)[idx];
    int a = (int)rintf(v.x / ws); a = max(-1, min(1, a));
    int b = (int)rintf(v.y / ws); b = max(-1, min(1, b));
    int c = (int)rintf(v.z / ws); c = max(-1, min(1, c));
    int d = (int)rintf(v.w / ws); d = max(-1, min(1, d));
    unsigned int p = (unsigned)(a & 255) | ((unsigned)(b & 255) << 8) |
                     ((unsigned)(c & 255) << 16) | ((unsigned)(d & 255) << 24);
    wq[idx] = p;
}

// ---------------- fused LayerNorm + pad + FWHT + int8 absmax quant ----------------
__global__ __launch_bounds__(256) void k_lnfwht(const float* __restrict__ x,
                                                const float* __restrict__ gamma,
                                                const float* __restrict__ beta,
                                                signed char* __restrict__ q,
                                                float* __restrict__ ainv) {
    __shared__ float s[PAD_F];
    __shared__ float rb[8];
    int tid = threadIdx.x;
    int lane = tid & 63;
    int t = blockIdx.x;
    const float* xr = x + (size_t)t * IN_F;

    float v[16];
    float sum = 0.f;
#pragma unroll
    for (int i = 0; i < 12; ++i) { v[i] = xr[tid + i * 256]; sum += v[i]; }
    v[12] = v[13] = v[14] = v[15] = 0.f;
#pragma unroll
    for (int o = 32; o > 0; o >>= 1) sum += __shfl_xor(sum, o);
    if ((tid & 63) == 0) rb[tid >> 6] = sum;
    __syncthreads();
    float mu = (rb[0] + rb[1] + rb[2] + rb[3]) * (1.0f / 3072.0f);

    float s2 = 0.f;
#pragma unroll
    for (int i = 0; i < 12; ++i) { float d = v[i] - mu; s2 += d * d; }
#pragma unroll
    for (int o = 32; o > 0; o >>= 1) s2 += __shfl_xor(s2, o);
    if ((tid & 63) == 0) rb[4 + (tid >> 6)] = s2;
    __syncthreads();
    float var = (rb[4] + rb[5] + rb[6] + rb[7]) * (1.0f / 3072.0f);
    float rstd = 1.0f / sqrtf(var + 1e-6f);

#pragma unroll
    for (int i = 0; i < 12; ++i)
        v[i] = (v[i] - mu) * rstd * gamma[tid + i * 256] + beta[tid + i * 256];

    // FWHT group 1: bits 8-11 (register index i)
#pragma unroll
    for (int b = 1; b < 16; b <<= 1) {
#pragma unroll
        for (int i = 0; i < 16; ++i) {
            if (!(i & b)) {
                float a0 = v[i], b0 = v[i | b];
                v[i] = a0 + b0;
                v[i | b] = a0 - b0;
            }
        }
    }
    // group 2: bits 0-5 (lane) via shfl_xor
#pragma unroll
    for (int m = 1; m <= 32; m <<= 1) {
#pragma unroll
        for (int i = 0; i < 16; ++i) {
            float p = __shfl_xor(v[i], m);
            v[i] = (lane & m) ? (p - v[i]) : (v[i] + p);
        }
    }
    // group 3: bits 6-7 (wave id) via LDS
#pragma unroll
    for (int m = 64; m <= 128; m <<= 1) {
        __syncthreads();
#pragma unroll
        for (int i = 0; i < 16; ++i) s[tid + i * 256] = v[i];
        __syncthreads();
#pragma unroll
        for (int i = 0; i < 16; ++i) {
            float p = s[(tid ^ m) + i * 256];
            v[i] = (tid & m) ? (p - v[i]) : (v[i] + p);
        }
    }

    // absmax of fwht/64
    float mx = 0.f;
#pragma unroll
    for (int i = 0; i < 16; ++i) mx = fmaxf(mx, fabsf(v[i]));
#pragma unroll
    for (int o = 32; o > 0; o >>= 1) mx = fmaxf(mx, __shfl_xor(mx, o));
    __syncthreads();
    if ((tid & 63) == 0) rb[tid >> 6] = mx;
    __syncthreads();
    float amraw = fmaxf(fmaxf(rb[0], rb[1]), fmaxf(rb[2], rb[3]));
    float amax = fmaxf(amraw * (1.0f / 64.0f), 1e-5f);
    float scale = 127.0f / amax;
    if (tid == 0) ainv[t] = amax * (1.0f / 127.0f);

    signed char* qr = q + (size_t)t * PAD_F;
#pragma unroll
    for (int i = 0; i < 16; ++i) {
        int qi = (int)rintf(v[i] * (1.0f / 64.0f) * scale);
        qi = max(-128, min(127, qi));
        qr[tid + i * 256] = (signed char)qi;
    }
}

// ---------------- int8 MFMA GEMM, 256x256 tile, BK=64, 4-phase/tile (m201-style) ----------------
// out[m][n] = (sum_k q[m][k]*t[n][k]) * wsc * ainv[m]
// 4-buffer LDS ring, stage tile t+3 spread as 1 gload per phase, vmcnt(8) once
// per tile (at P3; trailing barrier certifies cross-wave). LDS row = 64B = 4
// chunks of 16B at position chunk ^ ((row>>1)&3), realized via pre-swizzled
// global source (rule #21).
#define BK 64
#define NT (K_DIM / BK)   // 64

#define VMW(n) asm volatile("s_waitcnt vmcnt(" #n ")" ::: "memory")

__global__ __launch_bounds__(512, 2) void k_gemm(const signed char* __restrict__ Aq,
                                                 const signed char* __restrict__ Wq,
                                                 const float* __restrict__ ainv,
                                                 const float* __restrict__ wsp,
                                                 float* __restrict__ out) {
    __shared__ signed char sA[4][256 * BK];   // 4 x 16 KB
    __shared__ signed char sB[4][256 * BK];

    int tid = threadIdx.x;
    int lane = tid & 63, wid = tid >> 6;

    // XCD partition: XCD x owns bm in {4x..4x+3} (A L2-resident), sweeps bn.
    int bid = blockIdx.x;
    int xcd = bid & 7, li = bid >> 3;
    int bmb = xcd * 4 + (li & 3);
    int bnb = li >> 2;
    size_t bm0 = (size_t)bmb * 256, bn0 = (size_t)bnb * 256;

    int wm = wid >> 2, wn = wid & 3;          // 2M x 4N waves; wave tile 128x64

    // staging: lane -> row lane>>2 (16 rows/gload), source chunk (lane&3)^((lane>>3)&3)
    int srow = lane >> 2;
    int schunk = (lane & 3) ^ ((lane >> 3) & 3);
    const signed char* gA = Aq + (bm0 + (size_t)(wid * 32 + srow)) * K_DIM + schunk * 16;
    const signed char* gB = Wq + (bn0 + (size_t)(wid * 32 + srow)) * K_DIM + schunk * 16;

    // 32x32x32 fragment addressing: lane -> row r32 = lane&31, kseg = lane>>5 (16B)
    int r32 = lane & 31, ks32 = lane >> 5;
    int kq = ks32 ^ ((r32 >> 1) & 3);          // swizzled chunk for ks=0
    int kx0 = kq, kx1 = 2 ^ kq;                // ks=0 / ks=1 chunk positions
    int abase = (wm * 128 + r32) * 4;
    int bbase = (wn * 64 + r32) * 4;

    i32x16 acc[4][2];
#pragma unroll
    for (int mf = 0; mf < 4; ++mf)
#pragma unroll
        for (int nf = 0; nf < 2; ++nf) acc[mf][nf] = (i32x16)(0);

    i32x4 a0, a1, b0, b1;

#define MFMA_PHASE(M0, M1) do {                                              \
    __builtin_amdgcn_sched_barrier(0);                                       \
    __builtin_amdgcn_s_barrier();                                            \
    asm volatile("s_waitcnt lgkmcnt(0)" ::: "memory");                       \
    __builtin_amdgcn_sched_barrier(0);                                       \
    __builtin_amdgcn_s_setprio(1);                                           \
    acc[M0][0] = __builtin_amdgcn_mfma_i32_32x32x32_i8(a0, b0, acc[M0][0], 0, 0, 0); \
    acc[M0][1] = __builtin_amdgcn_mfma_i32_32x32x32_i8(a0, b1, acc[M0][1], 0, 0, 0); \
    acc[M1][0] = __builtin_amdgcn_mfma_i32_32x32x32_i8(a1, b0, acc[M1][0], 0, 0, 0); \
    acc[M1][1] = __builtin_amdgcn_mfma_i32_32x32x32_i8(a1, b1, acc[M1][1], 0, 0, 0); \
    __builtin_amdgcn_s_setprio(0);                                           \
    __builtin_amdgcn_s_barrier();                                            \
} while (0)

#define TILE(T, N, DS) do {                                                  \
    const i32x4* va = (const i32x4*)&sA[(T) & 3][0];                         \
    const i32x4* vb = (const i32x4*)&sB[(T) & 3][0];                         \
    signed char* nA = &sA[((T) + 3) & 3][0];                                 \
    signed char* nB = &sB[((T) + 3) & 3][0];                                 \
    size_t nk = (size_t)((T) + 3) * BK;                                      \
    /* P0: ks=0, mf 0-1 (+B) */                                              \
    a0 = va[abase + kx0];        a1 = va[abase + 128 + kx0];                 \
    b0 = vb[bbase + kx0];        b1 = vb[bbase + 128 + kx0];                 \
    if (DS) gload_lds16(gA + nk, nA + (wid * 32) * BK);                      \
    MFMA_PHASE(0, 1);                                                        \
    /* P1: ks=0, mf 2-3 */                                                   \
    a0 = va[abase + 256 + kx0];  a1 = va[abase + 384 + kx0];                 \
    if (DS) gload_lds16(gA + nk + (size_t)16 * K_DIM, nA + (wid * 32 + 16) * BK); \
    MFMA_PHASE(2, 3);                                                        \
    /* P2: ks=1, mf 0-1 (+B) */                                              \
    a0 = va[abase + kx1];        a1 = va[abase + 128 + kx1];                 \
    b0 = vb[bbase + kx1];        b1 = vb[bbase + 128 + kx1];                 \
    if (DS) gload_lds16(gB + nk, nB + (wid * 32) * BK);                      \
    MFMA_PHASE(0, 1);                                                        \
    /* P3: ks=1, mf 2-3; certify tile T+1 for next tile's reads */           \
    a0 = va[abase + 256 + kx1];  a1 = va[abase + 384 + kx1];                 \
    if (DS) gload_lds16(gB + nk + (size_t)16 * K_DIM, nB + (wid * 32 + 16) * BK); \
    VMW(N);                                                                  \
    MFMA_PHASE(2, 3);                                                        \
} while (0)

    // prologue: stage tiles 0,1,2 fully (12 loads); certify tile 0
    {
        for (int t = 0; t < 3; ++t) {
            size_t k0 = (size_t)t * BK;
            gload_lds16(gA + k0, &sA[t][(wid * 32) * BK]);
            gload_lds16(gA + k0 + (size_t)16 * K_DIM, &sA[t][(wid * 32 + 16) * BK]);
            gload_lds16(gB + k0, &sB[t][(wid * 32) * BK]);
            gload_lds16(gB + k0 + (size_t)16 * K_DIM, &sB[t][(wid * 32 + 16) * BK]);
        }
    }
    VMW(8);
    __builtin_amdgcn_s_barrier();

#pragma unroll 1
    for (int t = 0; t < NT - 3; ++t) TILE(t, 8, true);
    TILE(NT - 3, 4, false);
    TILE(NT - 2, 0, false);
    TILE(NT - 1, 0, false);

    // epilogue: 32x32 C/D layout: col = lane&31, row = (reg&3) + 8*(reg>>2) + 4*(lane>>5)
    float wsc = wsp[0];
    int c31 = lane & 31, hi2 = lane >> 5;
#pragma unroll
    for (int mf = 0; mf < 4; ++mf) {
        size_t rowb = bm0 + wm * 128 + mf * 32 + 4 * hi2;
#pragma unroll
        for (int reg = 0; reg < 16; ++reg) {
            size_t row = rowb + (reg & 3) + 8 * (reg >> 2);
            float sa = wsc * ainv[row];
#pragma unroll
            for (int nf = 0; nf < 2; ++nf) {
                size_t col = bn0 + wn * 64 + nf * 32 + c31;
                out[row * N_OUT + col] = (float)acc[mf][nf][reg] * sa;
            }
        }
    }
#undef MFMA_PHASE
#undef TILE
}

extern "C" void kernel_launch(void* const* d_in, const int* in_sizes, int n_in,
                              void* d_out, int out_size, void* d_ws, size_t ws_size,
                              hipStream_t stream) {
    const float* x     = (const float*)d_in[0];
    const float* gamma = (const float*)d_in[1];
    const float* beta  = (const float*)d_in[2];
    const float* w     = (const float*)d_in[3];
    float* out = (float*)d_out;
    char* ws = (char*)d_ws;

    signed char* q   = (signed char*)(ws + Q_OFF);
    signed char* wq  = (signed char*)(ws + WQ_OFF);
    float* ainv      = (float*)(ws + AINV_OFF);
    float* partial   = (float*)(ws + PART_OFF);
    float* wsp       = (float*)(ws + WSC_OFF);

    k_wabs<<<dim3(4096), dim3(256), 0, stream>>>(w, partial);
    k_wscale<<<dim3(1), dim3(256), 0, stream>>>(partial, wsp);
    k_wquant<<<dim3(16384), dim3(256), 0, stream>>>(w, wsp, (unsigned int*)wq);
    k_lnfwht<<<dim3(TOKENS), dim3(256), 0, stream>>>(x, gamma, beta, q, ainv);
    k_gemm<<<dim3(512), dim3(512), 0, stream>>>(q, wq, ainv, wsp, out);
}

// Round 6
// 213.383 us; speedup vs baseline: 1.1655x; 1.1655x over previous
//
#include <hip/hip_runtime.h>
#include <stdint.h>

// Problem dims
#define TOKENS 8192      // 4*2048
#define IN_F   3072
#define PAD_F  4096
#define N_OUT  4096
#define K_DIM  4096

using i32x4 = __attribute__((ext_vector_type(4))) int;

// -------- workspace layout (bytes) --------
#define Q_OFF    0
#define WQ_OFF   33554432
#define AINV_OFF 50331648
#define PART_OFF 50364416
#define WSC_OFF  50380800

__device__ __forceinline__ void gload_lds16(const void* g, void* l) {
    __builtin_amdgcn_global_load_lds(
        (__attribute__((address_space(1))) void*)(void*)g,
        (__attribute__((address_space(3))) void*)l,
        16, 0, 0);
}

// ---------------- weight absmean: partial sums ----------------
__global__ __launch_bounds__(256) void k_wabs(const float* __restrict__ w,
                                              float* __restrict__ partial) {
    int tid = threadIdx.x;
    const float4* w4 = (const float4*)(w + (size_t)blockIdx.x * 4096);
    float s = 0.f;
#pragma unroll
    for (int i = 0; i < 4; ++i) {
        float4 v = w4[tid + i * 256];
        s += fabsf(v.x) + fabsf(v.y) + fabsf(v.z) + fabsf(v.w);
    }
#pragma unroll
    for (int o = 32; o > 0; o >>= 1) s += __shfl_xor(s, o);
    __shared__ float rb[4];
    if ((tid & 63) == 0) rb[tid >> 6] = s;
    __syncthreads();
    if (tid == 0) partial[blockIdx.x] = rb[0] + rb[1] + rb[2] + rb[3];
}

// ---------------- finalize weight scale ----------------
__global__ __launch_bounds__(256) void k_wscale(const float* __restrict__ partial,
                                                float* __restrict__ wsp) {
    int tid = threadIdx.x;
    float s = 0.f;
#pragma unroll
    for (int i = 0; i < 16; ++i) s += partial[tid + i * 256];
#pragma unroll
    for (int o = 32; o > 0; o >>= 1) s += __shfl_xor(s, o);
    __shared__ float rb[4];
    if ((tid & 63) == 0) rb[tid >> 6] = s;
    __syncthreads();
    if (tid == 0)
        wsp[0] = fmaxf((rb[0] + rb[1] + rb[2] + rb[3]) * (1.0f / 16777216.0f), 1e-5f);
}

// ---------------- ternary weight quant ----------------
__global__ __launch_bounds__(256) void k_wquant(const float* __restrict__ w,
                                                const float* __restrict__ wsp,
                                                unsigned int* __restrict__ wq) {
    int idx = blockIdx.x * 256 + threadIdx.x;   // float4 group index
    float ws = wsp[0];
    float4 v = ((const float4*)w)[idx];
    int a = (int)rintf(v.x / ws); a = max(-1, min(1, a));
    int b = (int)rintf(v.y / ws); b = max(-1, min(1, b));
    int c = (int)rintf(v.z / ws); c = max(-1, min(1, c));
    int d = (int)rintf(v.w / ws); d = max(-1, min(1, d));
    unsigned int p = (unsigned)(a & 255) | ((unsigned)(b & 255) << 8) |
                     ((unsigned)(c & 255) << 16) | ((unsigned)(d & 255) << 24);
    wq[idx] = p;
}

// ---------------- fused LayerNorm + pad + FWHT + int8 absmax quant ----------------
__global__ __launch_bounds__(256) void k_lnfwht(const float* __restrict__ x,
                                                const float* __restrict__ gamma,
                                                const float* __restrict__ beta,
                                                signed char* __restrict__ q,
                                                float* __restrict__ ainv) {
    __shared__ float s[PAD_F];
    __shared__ float rb[8];
    int tid = threadIdx.x;
    int lane = tid & 63;
    int t = blockIdx.x;
    const float* xr = x + (size_t)t * IN_F;

    float v[16];
    float sum = 0.f;
#pragma unroll
    for (int i = 0; i < 12; ++i) { v[i] = xr[tid + i * 256]; sum += v[i]; }
    v[12] = v[13] = v[14] = v[15] = 0.f;
#pragma unroll
    for (int o = 32; o > 0; o >>= 1) sum += __shfl_xor(sum, o);
    if ((tid & 63) == 0) rb[tid >> 6] = sum;
    __syncthreads();
    float mu = (rb[0] + rb[1] + rb[2] + rb[3]) * (1.0f / 3072.0f);

    float s2 = 0.f;
#pragma unroll
    for (int i = 0; i < 12; ++i) { float d = v[i] - mu; s2 += d * d; }
#pragma unroll
    for (int o = 32; o > 0; o >>= 1) s2 += __shfl_xor(s2, o);
    if ((tid & 63) == 0) rb[4 + (tid >> 6)] = s2;
    __syncthreads();
    float var = (rb[4] + rb[5] + rb[6] + rb[7]) * (1.0f / 3072.0f);
    float rstd = 1.0f / sqrtf(var + 1e-6f);

#pragma unroll
    for (int i = 0; i < 12; ++i)
        v[i] = (v[i] - mu) * rstd * gamma[tid + i * 256] + beta[tid + i * 256];

    // FWHT group 1: bits 8-11 (register index i)
#pragma unroll
    for (int b = 1; b < 16; b <<= 1) {
#pragma unroll
        for (int i = 0; i < 16; ++i) {
            if (!(i & b)) {
                float a0 = v[i], b0 = v[i | b];
                v[i] = a0 + b0;
                v[i | b] = a0 - b0;
            }
        }
    }
    // group 2: bits 0-5 (lane) via shfl_xor
#pragma unroll
    for (int m = 1; m <= 32; m <<= 1) {
#pragma unroll
        for (int i = 0; i < 16; ++i) {
            float p = __shfl_xor(v[i], m);
            v[i] = (lane & m) ? (p - v[i]) : (v[i] + p);
        }
    }
    // group 3: bits 6-7 (wave id) via LDS
#pragma unroll
    for (int m = 64; m <= 128; m <<= 1) {
        __syncthreads();
#pragma unroll
        for (int i = 0; i < 16; ++i) s[tid + i * 256] = v[i];
        __syncthreads();
#pragma unroll
        for (int i = 0; i < 16; ++i) {
            float p = s[(tid ^ m) + i * 256];
            v[i] = (tid & m) ? (p - v[i]) : (v[i] + p);
        }
    }

    // absmax of fwht/64
    float mx = 0.f;
#pragma unroll
    for (int i = 0; i < 16; ++i) mx = fmaxf(mx, fabsf(v[i]));
#pragma unroll
    for (int o = 32; o > 0; o >>= 1) mx = fmaxf(mx, __shfl_xor(mx, o));
    __syncthreads();
    if ((tid & 63) == 0) rb[tid >> 6] = mx;
    __syncthreads();
    float amraw = fmaxf(fmaxf(rb[0], rb[1]), fmaxf(rb[2], rb[3]));
    float amax = fmaxf(amraw * (1.0f / 64.0f), 1e-5f);
    float scale = 127.0f / amax;
    if (tid == 0) ainv[t] = amax * (1.0f / 127.0f);

    signed char* qr = q + (size_t)t * PAD_F;
#pragma unroll
    for (int i = 0; i < 16; ++i) {
        int qi = (int)rintf(v[i] * (1.0f / 64.0f) * scale);
        qi = max(-128, min(127, qi));
        qr[tid + i * 256] = (signed char)qi;
    }
}

// ---------------- int8 MFMA GEMM, 256x256 tile, BK=64, paired-row LDS ----------------
// out[m][n] = (sum_k q[m][k]*t[n][k]) * wsc * ainv[m]
// LDS row r (128B) holds matrix rows {2r, 2r+1}; chunk (par,h) stored at
// position (par*4+h) ^ (r&7)  -> 16-row fragment reads are 2-way/distinct-addr
// = conflict-free (round-2-proven geometry). Staging pre-swizzles the GLOBAL
// source so global_load_lds writes linearly (rule #21).
// 4-buffer ring, counted vmcnt(8), register-fragment double-buffer:
// ds_read(t+1) issues before MFMA(t), lgkmcnt(0) only at body tail.
#define BK 64
#define NT (K_DIM / BK)   // 64

#define VMW(n) asm volatile("s_waitcnt vmcnt(" #n ")" ::: "memory")

__global__ __launch_bounds__(512, 2) void k_gemm(const signed char* __restrict__ Aq,
                                                 const signed char* __restrict__ Wq,
                                                 const float* __restrict__ ainv,
                                                 const float* __restrict__ wsp,
                                                 float* __restrict__ out) {
    __shared__ signed char sA[4][128 * 128];   // 4 x 16 KB (128 LDS-rows x 128B)
    __shared__ signed char sB[4][128 * 128];

    int tid = threadIdx.x;
    int lane = tid & 63, wid = tid >> 6;

    // XCD partition: XCD x owns bm in {4x..4x+3} (A L2-resident), sweeps bn.
    int bid = blockIdx.x;
    int xcd = bid & 7, li = bid >> 3;
    int bmb = xcd * 4 + (li & 3);
    int bnb = li >> 2;
    size_t bm0 = (size_t)bmb * 256, bn0 = (size_t)bnb * 256;

    int wm = wid >> 2, wn = wid & 3;          // 2M x 4N waves; wave tile 128x64

    // ---- staging decode: lane l writes LDS byte l*16 of a 1024B segment ----
    // LDS-row-in-seg rr = l>>3, slot p = l&7; logical L = p ^ rr (r&7 == rr),
    // par = L>>2 (matrix row parity), h = L&3 (16B K-chunk).
    int rr = lane >> 3, pp = lane & 7;
    int Lg = pp ^ rr;
    int spar = Lg >> 2, sh = Lg & 3;
    const signed char* gA = Aq + (bm0 + (size_t)(wid * 32 + 2 * rr + spar)) * K_DIM + sh * 16;
    const signed char* gB = Wq + (bn0 + (size_t)(wid * 32 + 2 * rr + spar)) * K_DIM + sh * 16;

    // ---- fragment read constants (16x16x64: frag row fr, kseg hh) ----
    int fr = lane & 15, hh = lane >> 4;
    int pos = (((fr & 1) << 2) | hh) ^ (fr >> 1);
    // A frag mf lives at LDS-rows wm*64 + mf*8 + (fr>>1); i32x4 index:
    int abase = (wm * 64 + (fr >> 1)) * 8 + pos;   // + mf*64
    int bbase = (wn * 32 + (fr >> 1)) * 8 + pos;   // + nf*64

    i32x4 acc[8][4];
#pragma unroll
    for (int m = 0; m < 8; ++m)
#pragma unroll
        for (int n = 0; n < 4; ++n) acc[m][n] = (i32x4){0, 0, 0, 0};

    i32x4 afA[8], bfA[4], afB[8], bfB[4];

    auto STAGE = [&](int b, int t) {
        size_t k0 = (size_t)t * BK;
        gload_lds16(gA + k0, &sA[b][(wid * 16) * 128]);
        gload_lds16(gA + k0 + (size_t)16 * K_DIM, &sA[b][(wid * 16 + 8) * 128]);
        gload_lds16(gB + k0, &sB[b][(wid * 16) * 128]);
        gload_lds16(gB + k0 + (size_t)16 * K_DIM, &sB[b][(wid * 16 + 8) * 128]);
    };

#define LOADF(B, AF, BF) do {                                           \
    const i32x4* va = (const i32x4*)&sA[B][0];                          \
    const i32x4* vb = (const i32x4*)&sB[B][0];                          \
    _Pragma("unroll")                                                   \
    for (int mf = 0; mf < 8; ++mf) AF[mf] = va[abase + mf * 64];        \
    _Pragma("unroll")                                                   \
    for (int nf = 0; nf < 4; ++nf) BF[nf] = vb[bbase + nf * 64];        \
} while (0)

#define COMPUTE(AF, BF) do {                                            \
    __builtin_amdgcn_s_setprio(1);                                      \
    _Pragma("unroll")                                                   \
    for (int mf = 0; mf < 8; ++mf)                                      \
        _Pragma("unroll")                                               \
        for (int nf = 0; nf < 4; ++nf)                                  \
            acc[mf][nf] = __builtin_amdgcn_mfma_i32_16x16x64_i8(        \
                AF[mf], BF[nf], acc[mf][nf], 0, 0, 0);                  \
    __builtin_amdgcn_s_setprio(0);                                      \
} while (0)

#define BODY(T, AFC, BFC, AFN, BFN) do {                                \
    STAGE((T + 3) & 3, T + 3);                                          \
    VMW(8);                                                             \
    __builtin_amdgcn_sched_barrier(0);                                  \
    __builtin_amdgcn_s_barrier();                                       \
    __builtin_amdgcn_sched_barrier(0);                                  \
    LOADF((T + 1) & 3, AFN, BFN);                                       \
    COMPUTE(AFC, BFC);                                                  \
    asm volatile("s_waitcnt lgkmcnt(0)" ::: "memory");                  \
    __builtin_amdgcn_sched_barrier(0);                                  \
} while (0)

    // prologue: 3 tiles in flight, tile 0 certified, frags(0) -> A set
    STAGE(0, 0);
    STAGE(1, 1);
    STAGE(2, 2);
    VMW(8);
    __builtin_amdgcn_sched_barrier(0);
    __builtin_amdgcn_s_barrier();
    __builtin_amdgcn_sched_barrier(0);
    LOADF(0, afA, bfA);
    asm volatile("s_waitcnt lgkmcnt(0)" ::: "memory");
    __builtin_amdgcn_sched_barrier(0);

#pragma unroll 1
    for (int t = 0; t < NT - 4; t += 2) {
        BODY(t, afA, bfA, afB, bfB);
        BODY(t + 1, afB, bfB, afA, bfA);
    }
    // t = 60: stages tile 63 (vmcnt(8) certifies 61), computes 60
    BODY(NT - 4, afA, bfA, afB, bfB);
    // t = 61: in-flight 62,63 -> vmcnt(4) certifies 62
    VMW(4);
    __builtin_amdgcn_sched_barrier(0);
    __builtin_amdgcn_s_barrier();
    __builtin_amdgcn_sched_barrier(0);
    LOADF(2, afA, bfA);
    COMPUTE(afB, bfB);
    asm volatile("s_waitcnt lgkmcnt(0)" ::: "memory");
    __builtin_amdgcn_sched_barrier(0);
    // t = 62: vmcnt(0) certifies 63
    VMW(0);
    __builtin_amdgcn_sched_barrier(0);
    __builtin_amdgcn_s_barrier();
    __builtin_amdgcn_sched_barrier(0);
    LOADF(3, afB, bfB);
    COMPUTE(afA, bfA);
    asm volatile("s_waitcnt lgkmcnt(0)" ::: "memory");
    __builtin_amdgcn_sched_barrier(0);
    // t = 63
    COMPUTE(afB, bfB);

    // epilogue: 16x16 C/D layout: col = lane&15, row = (lane>>4)*4 + reg
    float wsc = wsp[0];
#pragma unroll
    for (int mf = 0; mf < 8; ++mf) {
        size_t row0 = bm0 + wm * 128 + mf * 16 + hh * 4;
#pragma unroll
        for (int r = 0; r < 4; ++r) {
            size_t row = row0 + r;
            float sa = wsc * ainv[row];
#pragma unroll
            for (int nf = 0; nf < 4; ++nf) {
                size_t col = bn0 + wn * 64 + nf * 16 + fr;
                out[row * N_OUT + col] = (float)acc[mf][nf][r] * sa;
            }
        }
    }
#undef LOADF
#undef COMPUTE
#undef BODY
}

extern "C" void kernel_launch(void* const* d_in, const int* in_sizes, int n_in,
                              void* d_out, int out_size, void* d_ws, size_t ws_size,
                              hipStream_t stream) {
    const float* x     = (const float*)d_in[0];
    const float* gamma = (const float*)d_in[1];
    const float* beta  = (const float*)d_in[2];
    const float* w     = (const float*)d_in[3];
    float* out = (float*)d_out;
    char* ws = (char*)d_ws;

    signed char* q   = (signed char*)(ws + Q_OFF);
    signed char* wq  = (signed char*)(ws + WQ_OFF);
    float* ainv      = (float*)(ws + AINV_OFF);
    float* partial   = (float*)(ws + PART_OFF);
    float* wsp       = (float*)(ws + WSC_OFF);

    k_wabs<<<dim3(4096), dim3(256), 0, stream>>>(w, partial);
    k_wscale<<<dim3(1), dim3(256), 0, stream>>>(partial, wsp);
    k_wquant<<<dim3(16384), dim3(256), 0, stream>>>(w, wsp, (unsigned int*)wq);
    k_lnfwht<<<dim3(TOKENS), dim3(256), 0, stream>>>(x, gamma, beta, q, ainv);
    k_gemm<<<dim3(512), dim3(512), 0, stream>>>(q, wq, ainv, wsp, out);
}

// Round 7
// 211.388 us; speedup vs baseline: 1.1765x; 1.0094x over previous
//
#include <hip/hip_runtime.h>
#include <stdint.h>

// Problem dims
#define TOKENS 8192      // 4*2048
#define IN_F   3072
#define PAD_F  4096
#define N_OUT  4096
#define K_DIM  4096

using i32x4 = __attribute__((ext_vector_type(4))) int;

// -------- workspace layout (bytes) --------
#define Q_OFF    0
#define WQ_OFF   33554432
#define AINV_OFF 50331648
#define PART_OFF 50364416
#define WSC_OFF  50380800

__device__ __forceinline__ void gload_lds16(const void* g, void* l) {
    __builtin_amdgcn_global_load_lds(
        (__attribute__((address_space(1))) void*)(void*)g,
        (__attribute__((address_space(3))) void*)l,
        16, 0, 0);
}

// ---------------- weight absmean: partial sums ----------------
__global__ __launch_bounds__(256) void k_wabs(const float* __restrict__ w,
                                              float* __restrict__ partial) {
    int tid = threadIdx.x;
    const float4* w4 = (const float4*)(w + (size_t)blockIdx.x * 4096);
    float s = 0.f;
#pragma unroll
    for (int i = 0; i < 4; ++i) {
        float4 v = w4[tid + i * 256];
        s += fabsf(v.x) + fabsf(v.y) + fabsf(v.z) + fabsf(v.w);
    }
#pragma unroll
    for (int o = 32; o > 0; o >>= 1) s += __shfl_xor(s, o);
    __shared__ float rb[4];
    if ((tid & 63) == 0) rb[tid >> 6] = s;
    __syncthreads();
    if (tid == 0) partial[blockIdx.x] = rb[0] + rb[1] + rb[2] + rb[3];
}

// ---------------- finalize weight scale ----------------
__global__ __launch_bounds__(256) void k_wscale(const float* __restrict__ partial,
                                                float* __restrict__ wsp) {
    int tid = threadIdx.x;
    float s = 0.f;
#pragma unroll
    for (int i = 0; i < 16; ++i) s += partial[tid + i * 256];
#pragma unroll
    for (int o = 32; o > 0; o >>= 1) s += __shfl_xor(s, o);
    __shared__ float rb[4];
    if ((tid & 63) == 0) rb[tid >> 6] = s;
    __syncthreads();
    if (tid == 0)
        wsp[0] = fmaxf((rb[0] + rb[1] + rb[2] + rb[3]) * (1.0f / 16777216.0f), 1e-5f);
}

// ---------------- ternary weight quant ----------------
__global__ __launch_bounds__(256) void k_wquant(const float* __restrict__ w,
                                                const float* __restrict__ wsp,
                                                unsigned int* __restrict__ wq) {
    int idx = blockIdx.x * 256 + threadIdx.x;   // float4 group index
    float ws = wsp[0];
    float4 v = ((const float4*)w)[idx];
    int a = (int)rintf(v.x / ws); a = max(-1, min(1, a));
    int b = (int)rintf(v.y / ws); b = max(-1, min(1, b));
    int c = (int)rintf(v.z / ws); c = max(-1, min(1, c));
    int d = (int)rintf(v.w / ws); d = max(-1, min(1, d));
    unsigned int p = (unsigned)(a & 255) | ((unsigned)(b & 255) << 8) |
                     ((unsigned)(c & 255) << 16) | ((unsigned)(d & 255) << 24);
    wq[idx] = p;
}

// ---------------- fused LayerNorm + pad + FWHT + int8 absmax quant ----------------
__global__ __launch_bounds__(256) void k_lnfwht(const float* __restrict__ x,
                                                const float* __restrict__ gamma,
                                                const float* __restrict__ beta,
                                                signed char* __restrict__ q,
                                                float* __restrict__ ainv) {
    __shared__ float s[PAD_F];
    __shared__ float rb[8];
    int tid = threadIdx.x;
    int lane = tid & 63;
    int t = blockIdx.x;
    const float* xr = x + (size_t)t * IN_F;

    float v[16];
    float sum = 0.f;
#pragma unroll
    for (int i = 0; i < 12; ++i) { v[i] = xr[tid + i * 256]; sum += v[i]; }
    v[12] = v[13] = v[14] = v[15] = 0.f;
#pragma unroll
    for (int o = 32; o > 0; o >>= 1) sum += __shfl_xor(sum, o);
    if ((tid & 63) == 0) rb[tid >> 6] = sum;
    __syncthreads();
    float mu = (rb[0] + rb[1] + rb[2] + rb[3]) * (1.0f / 3072.0f);

    float s2 = 0.f;
#pragma unroll
    for (int i = 0; i < 12; ++i) { float d = v[i] - mu; s2 += d * d; }
#pragma unroll
    for (int o = 32; o > 0; o >>= 1) s2 += __shfl_xor(s2, o);
    if ((tid & 63) == 0) rb[4 + (tid >> 6)] = s2;
    __syncthreads();
    float var = (rb[4] + rb[5] + rb[6] + rb[7]) * (1.0f / 3072.0f);
    float rstd = 1.0f / sqrtf(var + 1e-6f);

#pragma unroll
    for (int i = 0; i < 12; ++i)
        v[i] = (v[i] - mu) * rstd * gamma[tid + i * 256] + beta[tid + i * 256];

    // FWHT group 1: bits 8-11 (register index i)
#pragma unroll
    for (int b = 1; b < 16; b <<= 1) {
#pragma unroll
        for (int i = 0; i < 16; ++i) {
            if (!(i & b)) {
                float a0 = v[i], b0 = v[i | b];
                v[i] = a0 + b0;
                v[i | b] = a0 - b0;
            }
        }
    }
    // group 2: bits 0-5 (lane) via shfl_xor
#pragma unroll
    for (int m = 1; m <= 32; m <<= 1) {
#pragma unroll
        for (int i = 0; i < 16; ++i) {
            float p = __shfl_xor(v[i], m);
            v[i] = (lane & m) ? (p - v[i]) : (v[i] + p);
        }
    }
    // group 3: bits 6-7 (wave id) via LDS
#pragma unroll
    for (int m = 64; m <= 128; m <<= 1) {
        __syncthreads();
#pragma unroll
        for (int i = 0; i < 16; ++i) s[tid + i * 256] = v[i];
        __syncthreads();
#pragma unroll
        for (int i = 0; i < 16; ++i) {
            float p = s[(tid ^ m) + i * 256];
            v[i] = (tid & m) ? (p - v[i]) : (v[i] + p);
        }
    }

    // absmax of fwht/64
    float mx = 0.f;
#pragma unroll
    for (int i = 0; i < 16; ++i) mx = fmaxf(mx, fabsf(v[i]));
#pragma unroll
    for (int o = 32; o > 0; o >>= 1) mx = fmaxf(mx, __shfl_xor(mx, o));
    __syncthreads();
    if ((tid & 63) == 0) rb[tid >> 6] = mx;
    __syncthreads();
    float amraw = fmaxf(fmaxf(rb[0], rb[1]), fmaxf(rb[2], rb[3]));
    float amax = fmaxf(amraw * (1.0f / 64.0f), 1e-5f);
    float scale = 127.0f / amax;
    if (tid == 0) ainv[t] = amax * (1.0f / 127.0f);

    signed char* qr = q + (size_t)t * PAD_F;
#pragma unroll
    for (int i = 0; i < 16; ++i) {
        int qi = (int)rintf(v[i] * (1.0f / 64.0f) * scale);
        qi = max(-128, min(127, qi));
        qr[tid + i * 256] = (signed char)qi;
    }
}

// ---------------- int8 MFMA GEMM, 256x256 tile, BK=64, paired-row LDS ----------------
// out[m][n] = (sum_k q[m][k]*t[n][k]) * wsc * ainv[m]
// LDS row r (128B) holds matrix rows {2r, 2r+1}; chunk (par,h) stored at
// position (par*4+h) ^ (r&7) -> conflict-free fragment reads (round-6 verified,
// SQ_LDS_BANK_CONFLICT = 0). Staging pre-swizzles the GLOBAL source (rule #21).
// 4-buffer ring, counted vmcnt(8), register-fragment double-buffer.
// NEW (round 7): sched_group_barrier pins {3 ds_read, 8 MFMA}x4 so the t+1
// fragment reads drain UNDER the tile-t MFMA cluster instead of after it.
#define BK 64
#define NT (K_DIM / BK)   // 64

#define VMW(n) asm volatile("s_waitcnt vmcnt(" #n ")" ::: "memory")

__global__ __launch_bounds__(512, 2) void k_gemm(const signed char* __restrict__ Aq,
                                                 const signed char* __restrict__ Wq,
                                                 const float* __restrict__ ainv,
                                                 const float* __restrict__ wsp,
                                                 float* __restrict__ out) {
    __shared__ signed char sA[4][128 * 128];   // 4 x 16 KB (128 LDS-rows x 128B)
    __shared__ signed char sB[4][128 * 128];

    int tid = threadIdx.x;
    int lane = tid & 63, wid = tid >> 6;

    // XCD partition: XCD x owns bm in {4x..4x+3} (A L2-resident), sweeps bn.
    int bid = blockIdx.x;
    int xcd = bid & 7, li = bid >> 3;
    int bmb = xcd * 4 + (li & 3);
    int bnb = li >> 2;
    size_t bm0 = (size_t)bmb * 256, bn0 = (size_t)bnb * 256;

    int wm = wid >> 2, wn = wid & 3;          // 2M x 4N waves; wave tile 128x64

    // ---- staging decode: lane l writes LDS byte l*16 of a 1024B segment ----
    int rr = lane >> 3, pp = lane & 7;
    int Lg = pp ^ rr;
    int spar = Lg >> 2, sh = Lg & 3;
    const signed char* gA = Aq + (bm0 + (size_t)(wid * 32 + 2 * rr + spar)) * K_DIM + sh * 16;
    const signed char* gB = Wq + (bn0 + (size_t)(wid * 32 + 2 * rr + spar)) * K_DIM + sh * 16;

    // ---- fragment read constants (16x16x64: frag row fr, kseg hh) ----
    int fr = lane & 15, hh = lane >> 4;
    int pos = (((fr & 1) << 2) | hh) ^ (fr >> 1);
    int abase = (wm * 64 + (fr >> 1)) * 8 + pos;   // + mf*64
    int bbase = (wn * 32 + (fr >> 1)) * 8 + pos;   // + nf*64

    i32x4 acc[8][4];
#pragma unroll
    for (int m = 0; m < 8; ++m)
#pragma unroll
        for (int n = 0; n < 4; ++n) acc[m][n] = (i32x4){0, 0, 0, 0};

    i32x4 afA[8], bfA[4], afB[8], bfB[4];

    auto STAGE = [&](int b, int t) {
        size_t k0 = (size_t)t * BK;
        gload_lds16(gA + k0, &sA[b][(wid * 16) * 128]);
        gload_lds16(gA + k0 + (size_t)16 * K_DIM, &sA[b][(wid * 16 + 8) * 128]);
        gload_lds16(gB + k0, &sB[b][(wid * 16) * 128]);
        gload_lds16(gB + k0 + (size_t)16 * K_DIM, &sB[b][(wid * 16 + 8) * 128]);
    };

#define LOADF(B, AF, BF) do {                                           \
    const i32x4* va = (const i32x4*)&sA[B][0];                          \
    const i32x4* vb = (const i32x4*)&sB[B][0];                          \
    _Pragma("unroll")                                                   \
    for (int mf = 0; mf < 8; ++mf) AF[mf] = va[abase + mf * 64];        \
    _Pragma("unroll")                                                   \
    for (int nf = 0; nf < 4; ++nf) BF[nf] = vb[bbase + nf * 64];        \
} while (0)

#define COMPUTE(AF, BF) do {                                            \
    __builtin_amdgcn_s_setprio(1);                                      \
    _Pragma("unroll")                                                   \
    for (int mf = 0; mf < 8; ++mf)                                      \
        _Pragma("unroll")                                               \
        for (int nf = 0; nf < 4; ++nf)                                  \
            acc[mf][nf] = __builtin_amdgcn_mfma_i32_16x16x64_i8(        \
                AF[mf], BF[nf], acc[mf][nf], 0, 0, 0);                  \
    __builtin_amdgcn_s_setprio(0);                                      \
} while (0)

// Pin compile-time interleave: 12 ds_read spread across the 32-MFMA cluster
// (masks per LLVM SchedGroupMask: DS_READ=0x100, MFMA=0x8)
#define SGB_PATTERN() do {                                              \
    __builtin_amdgcn_sched_group_barrier(0x100, 3, 0);                  \
    __builtin_amdgcn_sched_group_barrier(0x008, 8, 0);                  \
    __builtin_amdgcn_sched_group_barrier(0x100, 3, 0);                  \
    __builtin_amdgcn_sched_group_barrier(0x008, 8, 0);                  \
    __builtin_amdgcn_sched_group_barrier(0x100, 3, 0);                  \
    __builtin_amdgcn_sched_group_barrier(0x008, 8, 0);                  \
    __builtin_amdgcn_sched_group_barrier(0x100, 3, 0);                  \
    __builtin_amdgcn_sched_group_barrier(0x008, 8, 0);                  \
} while (0)

#define BODY(T, AFC, BFC, AFN, BFN) do {                                \
    STAGE((T + 3) & 3, T + 3);                                          \
    VMW(8);                                                             \
    __builtin_amdgcn_sched_barrier(0);                                  \
    __builtin_amdgcn_s_barrier();                                       \
    __builtin_amdgcn_sched_barrier(0);                                  \
    LOADF((T + 1) & 3, AFN, BFN);                                       \
    COMPUTE(AFC, BFC);                                                  \
    SGB_PATTERN();                                                      \
    asm volatile("s_waitcnt lgkmcnt(0)" ::: "memory");                  \
    __builtin_amdgcn_sched_barrier(0);                                  \
} while (0)

    // prologue: 3 tiles in flight, tile 0 certified, frags(0) -> A set
    STAGE(0, 0);
    STAGE(1, 1);
    STAGE(2, 2);
    VMW(8);
    __builtin_amdgcn_sched_barrier(0);
    __builtin_amdgcn_s_barrier();
    __builtin_amdgcn_sched_barrier(0);
    LOADF(0, afA, bfA);
    asm volatile("s_waitcnt lgkmcnt(0)" ::: "memory");
    __builtin_amdgcn_sched_barrier(0);

#pragma unroll 1
    for (int t = 0; t < NT - 4; t += 2) {
        BODY(t, afA, bfA, afB, bfB);
        BODY(t + 1, afB, bfB, afA, bfA);
    }
    // t = 60: stages tile 63 (vmcnt(8) certifies 61), computes 60
    BODY(NT - 4, afA, bfA, afB, bfB);
    // t = 61: in-flight 62,63 -> vmcnt(4) certifies 62
    VMW(4);
    __builtin_amdgcn_sched_barrier(0);
    __builtin_amdgcn_s_barrier();
    __builtin_amdgcn_sched_barrier(0);
    LOADF(2, afA, bfA);
    COMPUTE(afB, bfB);
    asm volatile("s_waitcnt lgkmcnt(0)" ::: "memory");
    __builtin_amdgcn_sched_barrier(0);
    // t = 62: vmcnt(0) certifies 63
    VMW(0);
    __builtin_amdgcn_sched_barrier(0);
    __builtin_amdgcn_s_barrier();
    __builtin_amdgcn_sched_barrier(0);
    LOADF(3, afB, bfB);
    COMPUTE(afA, bfA);
    asm volatile("s_waitcnt lgkmcnt(0)" ::: "memory");
    __builtin_amdgcn_sched_barrier(0);
    // t = 63
    COMPUTE(afB, bfB);

    // epilogue: 16x16 C/D layout: col = lane&15, row = (lane>>4)*4 + reg
    float wsc = wsp[0];
#pragma unroll
    for (int mf = 0; mf < 8; ++mf) {
        size_t row0 = bm0 + wm * 128 + mf * 16 + hh * 4;
#pragma unroll
        for (int r = 0; r < 4; ++r) {
            size_t row = row0 + r;
            float sa = wsc * ainv[row];
#pragma unroll
            for (int nf = 0; nf < 4; ++nf) {
                size_t col = bn0 + wn * 64 + nf * 16 + fr;
                out[row * N_OUT + col] = (float)acc[mf][nf][r] * sa;
            }
        }
    }
#undef LOADF
#undef COMPUTE
#undef SGB_PATTERN
#undef BODY
}

extern "C" void kernel_launch(void* const* d_in, const int* in_sizes, int n_in,
                              void* d_out, int out_size, void* d_ws, size_t ws_size,
                              hipStream_t stream) {
    const float* x     = (const float*)d_in[0];
    const float* gamma = (const float*)d_in[1];
    const float* beta  = (const float*)d_in[2];
    const float* w     = (const float*)d_in[3];
    float* out = (float*)d_out;
    char* ws = (char*)d_ws;

    signed char* q   = (signed char*)(ws + Q_OFF);
    signed char* wq  = (signed char*)(ws + WQ_OFF);
    float* ainv      = (float*)(ws + AINV_OFF);
    float* partial   = (float*)(ws + PART_OFF);
    float* wsp       = (float*)(ws + WSC_OFF);

    k_wabs<<<dim3(4096), dim3(256), 0, stream>>>(w, partial);
    k_wscale<<<dim3(1), dim3(256), 0, stream>>>(partial, wsp);
    k_wquant<<<dim3(16384), dim3(256), 0, stream>>>(w, wsp, (unsigned int*)wq);
    k_lnfwht<<<dim3(TOKENS), dim3(256), 0, stream>>>(x, gamma, beta, q, ainv);
    k_gemm<<<dim3(512), dim3(512), 0, stream>>>(q, wq, ainv, wsp, out);
}